// Round 6
// baseline (357.835 us; speedup 1.0000x reference)
//
#include <hip/hip_runtime.h>

// B=4, DIN=DM=256, N=256, L=64, H=4, LH=16.
// Block = (b, n, head-pair): grid = 2048, 512 threads (8 waves), LDS 67.5KB -> 2 blocks/CU.
// Round-6: round-4 diet (exp2 softmax w/ QSCALE folded into q-proj, tree max/sum,
// head-interleave, first-tile peel) with BOTH unverifiable idioms reverted to
// round-2-verified forms: pk2 = composed bit-twiddle RNE (no inline asm), and
// plain __launch_bounds__(512) (no min-waves clause).

typedef unsigned int u32;
typedef unsigned short u16;
typedef __attribute__((ext_vector_type(8))) short s8v;    // 8 x bf16
typedef __attribute__((ext_vector_type(16))) float f16v;  // 16 x f32 acc

#define XS 0        // X^T blocked: [cblk 0..31][l 0..31][j 0..7]  (8192) ; ATT after
#define QT 8192     // q^T blocked: [lblk 0..3][d 0..255][j 0..7]  (8192)
#define KT 16384    // k^T blocked
#define VT 24576    // v blocked: [eblk 0..31][l 0..31][j 0..7]
#define LDS_TOT 33792
#define LSTR 36     // linear staging row stride (u16)

#define QSCALE 0.360673760222f   // 0.25 * log2(e)

__device__ __forceinline__ u16 f2bf(float x) {          // round-2-verified RNE
  union { float f; u32 u; } c; c.f = x;
  return (u16)((c.u + 0x7FFFu + ((c.u >> 16) & 1u)) >> 16);
}
__device__ __forceinline__ u32 pk2(float a, float b) {  // round-2-verified composition
  return (u32)f2bf(a) | ((u32)f2bf(b) << 16);
}

// combine with lane^32 partner (round-2-verified forms)
__device__ __forceinline__ float xh_max(float v) {
  return fmaxf(v, __shfl_xor(v, 32));
}
__device__ __forceinline__ float xh_sum(float v) {
  return v + __shfl_xor(v, 32);
}

__global__ void cvt_weights(const float* __restrict__ wq, const float* __restrict__ wk,
                            const float* __restrict__ wv, const float* __restrict__ wo,
                            u16* __restrict__ out) {
  int i = blockIdx.x * 256 + threadIdx.x;  // 0..65535
  out[i]          = f2bf(wq[i]);
  out[i + 65536]  = f2bf(wk[i]);
  out[i + 131072] = f2bf(wv[i]);
  out[i + 196608] = f2bf(wo[i]);
}

// global fp32 X[c][l-window 32] -> linear bf16 lds[linoff + c*LSTR + l]
__device__ __forceinline__ void stage_lin(const float* __restrict__ src, u16* lds,
                                          int linoff, int tid) {
#pragma unroll
  for (int it = 0; it < 4; ++it) {
    int f4 = it * 512 + tid;           // 0..2047 float4s
    int c = f4 >> 3;
    int l4 = (f4 & 7) << 2;
    const float4 v = *reinterpret_cast<const float4*>(src + c * 16384 + l4);
    uint2 w; w.x = pk2(v.x, v.y); w.y = pk2(v.z, v.w);
    *reinterpret_cast<uint2*>(&lds[linoff + c * LSTR + l4]) = w;
  }
}

// linear lds[c][l] -> blocked XS[cblk][l][j]
__device__ __forceinline__ void lin_to_xs(u16* lds, int linoff, int tid) {
#pragma unroll
  for (int it = 0; it < 2; ++it) {
    int idx = it * 512 + tid;          // (cblk, l)
    int l = idx & 31, cb = idx >> 5;
    int sb = linoff + cb * (8 * LSTR) + l;
    u32 u0 = (u32)lds[sb]            | ((u32)lds[sb + LSTR]     << 16);
    u32 u1 = (u32)lds[sb + 2 * LSTR] | ((u32)lds[sb + 3 * LSTR] << 16);
    u32 u2 = (u32)lds[sb + 4 * LSTR] | ((u32)lds[sb + 5 * LSTR] << 16);
    u32 u3 = (u32)lds[sb + 6 * LSTR] | ((u32)lds[sb + 7 * LSTR] << 16);
    union { u32 u[4]; s8v v; } pw;
    pw.u[0] = u0; pw.u[1] = u1; pw.u[2] = u2; pw.u[3] = u3;
    *reinterpret_cast<s8v*>(&lds[XS + cb * 256 + l * 8]) = pw.v;
  }
}

// q^T / k^T: D[l][o] = (sum_c X^T[l][c] W[o][c] + b[o]) * osc
__device__ __forceinline__ void proj_T(u16* lds, const u16* __restrict__ w,
                                       const float* __restrict__ bias, int dst,
                                       float osc, int wid, int lo, int hi) {
  const int o = wid * 32 + lo;
  f16v a;
#pragma unroll
  for (int i = 0; i < 16; ++i) a[i] = 0.f;
#pragma unroll
  for (int s = 0; s < 16; ++s) {
    const s8v bw = *reinterpret_cast<const s8v*>(w + o * 256 + s * 16 + hi * 8);
    const s8v xf = *reinterpret_cast<const s8v*>(&lds[XS + (2 * s + hi) * 256 + lo * 8]);
    a = __builtin_amdgcn_mfma_f32_32x32x16_bf16(xf, bw, a, 0, 0, 0);
  }
  const float bb = bias[o];
#pragma unroll
  for (int g = 0; g < 4; ++g) {
    uint2 wv2;
    wv2.x = pk2((a[4 * g + 0] + bb) * osc, (a[4 * g + 1] + bb) * osc);
    wv2.y = pk2((a[4 * g + 2] + bb) * osc, (a[4 * g + 3] + bb) * osc);
    *reinterpret_cast<uint2*>(&lds[dst + g * 2048 + o * 8 + hi * 4]) = wv2;
  }
}

// v: D[e][l] = sum_c Wv[e][c] X[c][l] + bv[e]
__device__ __forceinline__ void proj_V(u16* lds, const u16* __restrict__ w,
                                       const float* __restrict__ bias,
                                       int wid, int lo, int hi) {
  const int e0 = wid * 32;
  const int e = e0 + lo;
  f16v a;
#pragma unroll
  for (int i = 0; i < 16; ++i) a[i] = 0.f;
#pragma unroll
  for (int s = 0; s < 16; ++s) {
    const s8v aw = *reinterpret_cast<const s8v*>(w + e * 256 + s * 16 + hi * 8);
    const s8v xf = *reinterpret_cast<const s8v*>(&lds[XS + (2 * s + hi) * 256 + lo * 8]);
    a = __builtin_amdgcn_mfma_f32_32x32x16_bf16(aw, xf, a, 0, 0, 0);
  }
#pragma unroll
  for (int g = 0; g < 4; ++g) {
    const int eb = e0 + 8 * g + 4 * hi;
    uint2 wv2;
    wv2.x = pk2(a[4 * g + 0] + bias[eb + 0], a[4 * g + 1] + bias[eb + 1]);
    wv2.y = pk2(a[4 * g + 2] + bias[eb + 2], a[4 * g + 3] + bias[eb + 3]);
    *reinterpret_cast<uint2*>(&lds[VT + (4 * wid + g) * 256 + lo * 8 + hi * 4]) = wv2;
  }
}

// out[o][l] = sum_d Wo[o][d] att[d][l] + bo[o]
__device__ __forceinline__ void proj_O(u16* lds, const u16* __restrict__ w,
                                       const float* __restrict__ bias,
                                       float* __restrict__ out, long obase,
                                       int wid, int lo, int hi) {
  const int o0 = wid * 32;
  const int o = o0 + lo;
  f16v a;
#pragma unroll
  for (int i = 0; i < 16; ++i) a[i] = 0.f;
#pragma unroll
  for (int s = 0; s < 16; ++s) {
    const s8v aw = *reinterpret_cast<const s8v*>(w + o * 256 + s * 16 + hi * 8);
    const s8v bf = *reinterpret_cast<const s8v*>(&lds[XS + (2 * s + hi) * 256 + lo * 8]);
    a = __builtin_amdgcn_mfma_f32_32x32x16_bf16(aw, bf, a, 0, 0, 0);
  }
#pragma unroll
  for (int r = 0; r < 16; ++r) {
    const int orow = o0 + (r & 3) + 8 * (r >> 2) + 4 * hi;
    out[obase + orow * 16384 + lo] = a[r] + bias[orow];
  }
}

__global__ __launch_bounds__(512)
void mha_kernel(const float* __restrict__ xq, const float* __restrict__ xk,
                const float* __restrict__ xv, const u16* __restrict__ wb,
                const float* __restrict__ bq, const float* __restrict__ bk,
                const float* __restrict__ bv, const float* __restrict__ bo,
                float* __restrict__ out) {
  __shared__ __align__(16) u16 lds[LDS_TOT];
  const int tid = threadIdx.x;
  const int lane = tid & 63;
  const int wid = tid >> 6;
  const int lo = lane & 31;
  const int hi = lane >> 5;
  const int hp = blockIdx.x & 1;
  const int n = (blockIdx.x >> 1) & 255;
  const int b = blockIdx.x >> 9;
  const long base = (long)b * 4194304 + n * 64 + hp * 32;

  // ---- staged projections ----
  stage_lin(xq + base, lds, KT, tid);
  __syncthreads();
  lin_to_xs(lds, KT, tid);
  __syncthreads();
  stage_lin(xk + base, lds, KT, tid);
  proj_T(lds, wb + 0, bq, QT, QSCALE, wid, lo, hi);
  __syncthreads();
  lin_to_xs(lds, KT, tid);
  __syncthreads();
  stage_lin(xv + base, lds, VT, tid);
  proj_T(lds, wb + 65536, bk, KT, 1.0f, wid, lo, hi);
  __syncthreads();
  lin_to_xs(lds, VT, tid);
  __syncthreads();
  proj_V(lds, wb + 131072, bv, wid, lo, hi);
  __syncthreads();

  // ---- attention: online softmax, two heads interleaved ----
  f16v z16;
#pragma unroll
  for (int i = 0; i < 16; ++i) z16[i] = 0.f;
  const int l15 = lane & 15;

  s8v qf[2];
  qf[0] = *reinterpret_cast<const s8v*>(&lds[QT + (0 + hi) * 2048 + (wid * 32 + lo) * 8]);
  qf[1] = *reinterpret_cast<const s8v*>(&lds[QT + (2 + hi) * 2048 + (wid * 32 + lo) * 8]);

  f16v ot[2];
  float m[2], sm[2];
#pragma unroll
  for (int h = 0; h < 2; ++h) {
#pragma unroll
    for (int i = 0; i < 16; ++i) ot[h][i] = 0.f;
    m[h] = 0.f; sm[h] = 0.f;
  }

#pragma unroll
  for (int et = 0; et < 8; ++et) {
    f16v st[2];
#pragma unroll
    for (int h = 0; h < 2; ++h) {
      const s8v kf = *reinterpret_cast<const s8v*>(
          &lds[KT + (2 * h + hi) * 2048 + (et * 32 + lo) * 8]);
      st[h] = __builtin_amdgcn_mfma_f32_32x32x16_bf16(kf, qf[h], z16, 0, 0, 0);
    }
#pragma unroll
    for (int h = 0; h < 2; ++h) {
      // depth-4 tree max over 16, then cross-half combine
      float t[8];
#pragma unroll
      for (int i = 0; i < 8; ++i) t[i] = fmaxf(st[h][i], st[h][i + 8]);
#pragma unroll
      for (int i = 0; i < 4; ++i) t[i] = fmaxf(t[i], t[i + 4]);
      float tm = xh_max(fmaxf(fmaxf(t[0], t[1]), fmaxf(t[2], t[3])));

      if (et == 0) {
        m[h] = tm;                      // peel: no rescale on first tile
      } else {
        const float mn = fmaxf(m[h], tm);
        const float f = __builtin_amdgcn_exp2f(m[h] - mn);
        m[h] = mn;
        sm[h] *= f;
#pragma unroll
        for (int i = 0; i < 16; ++i) ot[h][i] *= f;
      }
      // p = exp2(st - m)  (q pre-scaled by 0.25*log2e)
      float p[16];
#pragma unroll
      for (int i = 0; i < 16; ++i) p[i] = __builtin_amdgcn_exp2f(st[h][i] - m[h]);
      float s[8];
#pragma unroll
      for (int i = 0; i < 8; ++i) s[i] = p[i] + p[i + 8];
#pragma unroll
      for (int i = 0; i < 4; ++i) s[i] = s[i] + s[i + 4];
      sm[h] += (s[0] + s[1]) + (s[2] + s[3]);

      // PV accumulate: 2 k-steps of 16  (round-2-verified shfl_xor pack)
#pragma unroll
      for (int s2 = 0; s2 < 2; ++s2) {
        const int ks = 2 * et + s2;
        const s8v vf = *reinterpret_cast<const s8v*>(
            &lds[VT + (2 * ks + hi) * 256 + (h * 16 + l15) * 8]);
        const int q = s2 * 8;
        const u32 x0 = pk2(p[q + 0], p[q + 1]);
        const u32 x1 = pk2(p[q + 2], p[q + 3]);
        const u32 y0 = pk2(p[q + 4], p[q + 5]);
        const u32 y1 = pk2(p[q + 6], p[q + 7]);
        const u32 sx0 = (u32)__shfl_xor((int)x0, 32);
        const u32 sx1 = (u32)__shfl_xor((int)x1, 32);
        const u32 sy0 = (u32)__shfl_xor((int)y0, 32);
        const u32 sy1 = (u32)__shfl_xor((int)y1, 32);
        union { u32 u[4]; s8v v; } bu;
        bu.u[0] = hi ? sy0 : x0;
        bu.u[1] = hi ? sy1 : x1;
        bu.u[2] = hi ? y0 : sx0;
        bu.u[3] = hi ? y1 : sx1;
        ot[h] = __builtin_amdgcn_mfma_f32_32x32x16_bf16(vf, bu.v, ot[h], 0, 0, 0);
      }
    }
  }

  // finalize + store O^T into ATT (@XS)
#pragma unroll
  for (int h = 0; h < 2; ++h) {
    const float rinv = 1.0f / xh_sum(sm[h]);
    const int d = wid * 32 + lo;
#pragma unroll
    for (int r = 0; r < 8; ++r) {
      const int lh = (r & 3) + 8 * (r >> 2) + 4 * hi;   // 0..15
      const int l = h * 16 + lh;
      lds[XS + (d >> 3) * 256 + l * 8 + (d & 7)] = f2bf(ot[h][r] * rinv);
    }
  }
  __syncthreads();

  proj_O(lds, wb + 196608, bo, out, base, wid, lo, hi);
}

extern "C" void kernel_launch(void* const* d_in, const int* in_sizes, int n_in,
                              void* d_out, int out_size, void* d_ws, size_t ws_size,
                              hipStream_t stream) {
  const float* xq = (const float*)d_in[0];
  const float* xk = (const float*)d_in[1];
  const float* xv = (const float*)d_in[2];
  const float* wq = (const float*)d_in[3];
  const float* bq = (const float*)d_in[4];
  const float* wk = (const float*)d_in[5];
  const float* bk = (const float*)d_in[6];
  const float* wv = (const float*)d_in[7];
  const float* bv = (const float*)d_in[8];
  const float* wo = (const float*)d_in[9];
  const float* bo = (const float*)d_in[10];
  u16* wsb = (u16*)d_ws;  // 4 * 65536 bf16 = 512 KB
  float* out = (float*)d_out;

  cvt_weights<<<dim3(256), dim3(256), 0, stream>>>(wq, wk, wv, wo, wsb);
  mha_kernel<<<dim3(2048), dim3(512), 0, stream>>>(xq, xk, xv, wsb, bq, bk, bv, bo, out);
}